// Round 1
// baseline (275.171 us; speedup 1.0000x reference)
//
#include <hip/hip_runtime.h>

// Encoder: 2-layer LSTM (H=16 each), x [B=16384, T=100, I=18], FP32 in/out.
// R7: producer/consumer layer split. R6 ran 1 wave/SIMD (Occupancy 11%) with
// VALUBusy 51% + MfmaUtil 17.5% -> ~32% dead time = un-hidable MFMA/trans
// latency. Split each 16-batch tile into TWO waves: role 0 runs L1 (20 MFMA +
// ew + x-convert pipeline), role 1 runs L2 (16 MFMA + ew). The packed h1
// dwords are lane-for-lane the L2 B-fragment (producer lane (g,b) holds units
// 4g..4g+3 of batch b = consumer lane (g,b)'s k-slots), so handoff is one
// ds_write_b128/ds_read_b128 through a double-buffered 2KB LDS buffer.
// 1024 blocks x 128 thr = 2048 waves = 2 waves/SIMD: each wave's stalls hide
// under the other's issue (MFMA and VALU pipes co-issue across waves, m114).
// Sync: ONE raw s_barrier per wave per timestep with lgkmcnt(0) only --
// NOT __syncthreads(), whose vmcnt(0) drain would serialize the 3-step
// x prefetch. Race-free: L1 writes buf[t&1] < B(t) < L2 reads buf[t&1]
// < B(t+1) < L1 rewrites buf[t&1] (double buffer, 1 barrier/iter).
// Role XOR block parity so co-resident blocks tend to mix roles per SIMD.
// PRECISION: bit-identical math to R6 (trunc two-term splits at runtime,
// RNE splits for weights, fp32 gate math); R6 measured absmax 9.77e-4 vs
// 3.9e-3 threshold. (Deferred micro-opt for next round: v_perm_b32 for
// split_pack/cvt_pair, ~28 VALU/iter.)

typedef float f32x4 __attribute__((ext_vector_type(4)));
typedef __bf16 bf16x8 __attribute__((ext_vector_type(8)));
typedef unsigned int uint32x4 __attribute__((ext_vector_type(4)));

union FragU { bf16x8 v; unsigned short u[8]; unsigned int d[4]; uint32x4 q; };

#define MFMA16(A, B, C) __builtin_amdgcn_mfma_f32_16x16x32_bf16((A), (B), (C), 0, 0, 0)

static __device__ __forceinline__ unsigned short f2bf(float f) {  // RNE (weights)
  unsigned int u = __builtin_bit_cast(unsigned int, f);
  u = u + 0x7FFFu + ((u >> 16) & 1u);
  return (unsigned short)(u >> 16);
}
static __device__ __forceinline__ float bfbits2f(unsigned short h) {
  unsigned int u = ((unsigned int)h) << 16;
  return __builtin_bit_cast(float, u);
}
static __device__ __forceinline__ float sigm(float x) {
  // 1/(1+exp(-x)); saturates cleanly, never NaN for finite x.
  return __builtin_amdgcn_rcpf(1.0f + __builtin_amdgcn_exp2f(x * -1.4426950408889634f));
}
static __device__ __forceinline__ float tanh_(float x) {
  // 1 - 2/(1+exp(2x)); saturates to +-1.
  return 1.0f - 2.0f * __builtin_amdgcn_rcpf(1.0f + __builtin_amdgcn_exp2f(x * 2.8853900817779268f));
}
// Trunc two-term split packed as (bf_hi | bf_lo<<16). hi+lo == v to 2^-16|v|.
static __device__ __forceinline__ unsigned int split_pack(float v) {
  unsigned int u = __builtin_bit_cast(unsigned int, v);
  float hf = __builtin_bit_cast(float, u & 0xFFFF0000u);
  unsigned int l = __builtin_bit_cast(unsigned int, v - hf);
  return (u >> 16) | (l & 0xFFFF0000u);
}
// Split a float pair into hi-frag dword and lo-frag dword.
static __device__ __forceinline__ void cvt_pair(float f0, float f1,
                                                unsigned int& hd, unsigned int& ld) {
  unsigned int u0 = __builtin_bit_cast(unsigned int, f0);
  unsigned int u1 = __builtin_bit_cast(unsigned int, f1);
  unsigned int h0 = u0 & 0xFFFF0000u;
  unsigned int h1 = u1 & 0xFFFF0000u;
  hd = (u0 >> 16) | h1;
  unsigned int l0 = __builtin_bit_cast(unsigned int, f0 - __builtin_bit_cast(float, h0));
  unsigned int l1 = __builtin_bit_cast(unsigned int, f1 - __builtin_bit_cast(float, h1));
  ld = (l0 >> 16) | (l1 & 0xFFFF0000u);
}

// Raw barrier: lgkmcnt(0) drains the ds_write/ds_read queue, "memory" clobber
// pins LDS ops on the correct side at compile time; vmcnt stays in flight so
// the x prefetch pipeline survives the barrier.
static __device__ __forceinline__ void wg_barrier() {
  asm volatile("s_waitcnt lgkmcnt(0)" ::: "memory");
  __builtin_amdgcn_s_barrier();
}

struct RawX { float2 a, b2, c, d; };

__global__ __launch_bounds__(128, 2) void enc_kernel(
    const float* __restrict__ x,     // [16384,100,18]
    const float* __restrict__ Wih1,  // [64,18]
    const float* __restrict__ Whh1,  // [64,16]
    const float* __restrict__ bih1,  // [64]
    const float* __restrict__ bhh1,  // [64]
    const float* __restrict__ Wih2,  // [64,16]
    const float* __restrict__ Whh2,  // [64,16]
    const float* __restrict__ bih2,  // [64]
    const float* __restrict__ bhh2,  // [64]
    float* __restrict__ out)         // [16384,16]
{
  const int lane = threadIdx.x & 63;
  const int b    = lane & 15;  // batch in tile: A m-row / B n-col / C col
  const int g    = lane >> 4;  // k-group; C row-quad (units 4g..4g+3)

  // One block = one 16-batch tile = {L1 wave, L2 wave}. Role XOR block parity.
  const int role = ((int)(threadIdx.x >> 6) ^ (int)blockIdx.x) & 1;
  const int b0   = (int)blockIdx.x * 16;

  // Double-buffered h1 handoff: 2 x 64 lanes x 16B = 2 KB.
  __shared__ uint32x4 hxc[2][64];

  if (role == 0) {
    // =================== L1 (producer) wave ===================
    FragU A1h[4], A1l[4], A2h[4], A2l[4];
    f32x4 bias1v[4];
#pragma unroll
    for (int tn = 0; tn < 4; ++tn) {  // 0=i 1=f 2=g 3=o (PyTorch gate order)
      const int row = tn * 16 + b;
#pragma unroll
      for (int j = 0; j < 8; ++j) {
        const int k = 8 * g + j;
        if (k < 18) {
          const float w = Wih1[row * 18 + k];
          A1h[tn].u[j] = f2bf(w);
          A1l[tn].u[j] = f2bf(w - bfbits2f(A1h[tn].u[j]));
        } else {
          A1h[tn].u[j] = 0;
          A1l[tn].u[j] = 0;
        }
        const int kk = k >> 1;  // hi/lo interleave: both K slots share the weight
        const float w2 = Whh1[row * 16 + kk];
        A2h[tn].u[j] = f2bf(w2); A2l[tn].u[j] = f2bf(w2 - bfbits2f(A2h[tn].u[j]));
      }
#pragma unroll
      for (int r = 0; r < 4; ++r) {
        const int u4 = tn * 16 + 4 * g + r;  // C row = unit 4g+r of gate tn
        bias1v[tn][r] = bih1[u4] + bhh1[u4];
      }
    }

    // ---- x addressing: lane (b,g) covers x[b0+b][t][8g .. 8g+7] ----
    const float* const x0 = x + (size_t)(b0 + b) * 1800 + 8 * g;
    const int adv = (g == 3) ? 0 : 18;

    auto loadraw = [&](const float* p) -> RawX {
      RawX r;
      r.a = *(const float2*)p;  // g<2: k 8g..8g+1; g==2: k 16,17; g==3: dummy
      if (g < 2) {              // full 8 features, in-bounds for all t
        r.b2 = *(const float2*)(p + 2);
        r.c  = *(const float2*)(p + 4);
        r.d  = *(const float2*)(p + 6);
      } else {                  // g>=2: only pair a matters (k>=18 hits A-pad)
        r.b2 = r.c = r.d = make_float2(0.f, 0.f);
      }
      return r;
    };
    auto cvt = [&](const RawX& rw_, FragU& hi, FragU& lo) {
      cvt_pair(rw_.a.x, rw_.a.y, hi.d[0], lo.d[0]);
      cvt_pair(rw_.b2.x, rw_.b2.y, hi.d[1], lo.d[1]);
      cvt_pair(rw_.c.x, rw_.c.y, hi.d[2], lo.d[2]);
      cvt_pair(rw_.d.x, rw_.d.y, hi.d[3], lo.d[3]);
    };

    // ---- prologue: raw x for t=0,1,2 in flight together ----
    RawX rw0 = loadraw(x0);
    RawX rw1 = loadraw(x0 + adv);
    RawX rw  = loadraw(x0 + 2 * adv);
    const float* xq = x0 + 3 * adv;  // next load target: t=3

    FragU hb;
    hb.q = (uint32x4){0u, 0u, 0u, 0u};  // h1_{-1}
    float c1[4] = {0.f, 0.f, 0.f, 0.f};

    FragU xch, xcl;
    cvt(rw0, xch, xcl);  // x(0)

    // ga = L1 gate preacts for t=0 (hb = 0)
    f32x4 ga[4];
#pragma unroll
    for (int tn = 0; tn < 4; ++tn) {
      f32x4 acc = MFMA16(A1h[tn].v, xch.v, bias1v[tn]);
      acc = MFMA16(A1l[tn].v, xch.v, acc);
      acc = MFMA16(A1h[tn].v, xcl.v, acc);
      acc = MFMA16(A2h[tn].v, hb.v, acc);
      acc = MFMA16(A2l[tn].v, hb.v, acc);
      ga[tn] = acc;
    }
    cvt(rw1, xch, xcl);  // x(1) ready for the loop's L1-MFMAs(t+1)

#pragma unroll 2
    for (int t = 0; t < 100; ++t) {
      // ---- L1 elementwise (t): ga -> h1(t) packed; relu'd copy to LDS ----
      FragU rb;
#pragma unroll
      for (int r = 0; r < 4; ++r) {
        const float iv = sigm(ga[0][r]);
        const float fv = sigm(ga[1][r]);
        const float gv = tanh_(ga[2][r]);
        const float ov = sigm(ga[3][r]);
        const float cc = fv * c1[r] + iv * gv;
        c1[r] = cc;
        const float h = ov * tanh_(cc);
        const unsigned int pk = split_pack(h);
        hb.d[r] = pk;
        rb.d[r] = (h > 0.f) ? pk : 0u;  // relu: identical split when positive
      }
      hxc[t & 1][lane] = rb.q;  // ds_write_b128, lane-for-lane = L2 B-frag

      // ---- L1 MFMAs (t+1): in-register recurrence via hb ----
      f32x4 gan[4];
#pragma unroll
      for (int tn = 0; tn < 4; ++tn) {
        f32x4 acc = MFMA16(A1h[tn].v, xch.v, bias1v[tn]);
        acc = MFMA16(A1l[tn].v, xch.v, acc);
        acc = MFMA16(A1h[tn].v, xcl.v, acc);
        acc = MFMA16(A2h[tn].v, hb.v, acc);
        acc = MFMA16(A2l[tn].v, hb.v, acc);
        gan[tn] = acc;
      }

      // ---- convert x(t+2) from raw regs; issue raw load x(t+3) ----
      FragU nxh, nxl;
      cvt(rw, nxh, nxl);
      RawX rwn = loadraw((t <= 96) ? xq : x0);  // uniform guard past the end
      xq += adv;

      // rotate pipeline registers (elided by unroll-2 ping-pong)
#pragma unroll
      for (int tn = 0; tn < 4; ++tn) ga[tn] = gan[tn];
      xch = nxh;
      xcl = nxl;
      rw = rwn;

      wg_barrier();  // B(t): publishes h1(t); MFMA latency drains here too
    }
    // L1 wave done: 100 barriers executed, matches L2's count. No output.
  } else {
    // =================== L2 (consumer) wave ===================
    FragU A3h[4], A3l[4], A4h[4], A4l[4];
    f32x4 bias2v[4];
#pragma unroll
    for (int tn = 0; tn < 4; ++tn) {
      const int row = tn * 16 + b;
#pragma unroll
      for (int j = 0; j < 8; ++j) {
        const int kk = (8 * g + j) >> 1;  // hi/lo interleave
        const float w3 = Wih2[row * 16 + kk];
        const float w4 = Whh2[row * 16 + kk];
        A3h[tn].u[j] = f2bf(w3); A3l[tn].u[j] = f2bf(w3 - bfbits2f(A3h[tn].u[j]));
        A4h[tn].u[j] = f2bf(w4); A4l[tn].u[j] = f2bf(w4 - bfbits2f(A4h[tn].u[j]));
      }
#pragma unroll
      for (int r = 0; r < 4; ++r) {
        const int u4 = tn * 16 + 4 * g + r;
        bias2v[tn][r] = bih2[u4] + bhh2[u4];
      }
    }

    FragU h2b;
    h2b.q = (uint32x4){0u, 0u, 0u, 0u};  // h2_{-1}
    float c2[4] = {0.f, 0.f, 0.f, 0.f};
    float h2v[4] = {0.f, 0.f, 0.f, 0.f};

#pragma unroll 2
    for (int t = 0; t < 100; ++t) {
      wg_barrier();  // B(t): hxc[t&1] now holds relu(h1(t))

      FragU rbp;
      rbp.q = hxc[t & 1][lane];  // ds_read_b128

      // ---- L2 MFMAs (t): h2 recurrence stays in registers ----
      f32x4 gb[4];
#pragma unroll
      for (int tn = 0; tn < 4; ++tn) {
        f32x4 acc = MFMA16(A4h[tn].v, h2b.v, bias2v[tn]);
        acc = MFMA16(A4l[tn].v, h2b.v, acc);
        acc = MFMA16(A3h[tn].v, rbp.v, acc);
        acc = MFMA16(A3l[tn].v, rbp.v, acc);
        gb[tn] = acc;
      }

      // ---- L2 elementwise (t) ----
#pragma unroll
      for (int r = 0; r < 4; ++r) {
        const float iv = sigm(gb[0][r]);
        const float fv = sigm(gb[1][r]);
        const float gv = tanh_(gb[2][r]);
        const float ov = sigm(gb[3][r]);
        const float cc = fv * c2[r] + iv * gv;
        c2[r] = cc;
        const float h = ov * tanh_(cc);
        h2v[r] = h;
        h2b.d[r] = split_pack(h);
      }
    }

    // ---- output: relu(h2_last); lane (b,g) holds units 4g..4g+3 of batch b ----
    f32x4 o;
#pragma unroll
    for (int r = 0; r < 4; ++r) o[r] = fmaxf(h2v[r], 0.f);
    *(f32x4*)(out + (size_t)(b0 + b) * 16 + 4 * g) = o;  // 16B-aligned
  }
}

extern "C" void kernel_launch(void* const* d_in, const int* in_sizes, int n_in,
                              void* d_out, int out_size, void* d_ws, size_t ws_size,
                              hipStream_t stream) {
  (void)in_sizes; (void)n_in; (void)d_ws; (void)ws_size; (void)out_size;
  // 16384 batch / 16 per tile = 1024 blocks x 128 threads (L1 wave + L2 wave).
  // 4 blocks/CU -> 8 waves/CU -> 2 waves/SIMD.
  enc_kernel<<<dim3(1024), dim3(128), 0, stream>>>(
      (const float*)d_in[0],
      (const float*)d_in[1],
      (const float*)d_in[2],
      (const float*)d_in[3],
      (const float*)d_in[4],
      (const float*)d_in[5],
      (const float*)d_in[6],
      (const float*)d_in[7],
      (const float*)d_in[8],
      (float*)d_out);
}